// Round 2
// baseline (252.332 us; speedup 1.0000x reference)
//
#include <hip/hip_runtime.h>
#include <stdint.h>

typedef unsigned short u16;
typedef u16   u16x4    __attribute__((ext_vector_type(4)));
typedef u16   u16x8    __attribute__((ext_vector_type(8)));
typedef u16x8 u16x8_ma __attribute__((may_alias));
typedef __bf16 bf16x8  __attribute__((ext_vector_type(8)));
typedef float f32x4    __attribute__((ext_vector_type(4)));
typedef f32x4 f32x4_ma __attribute__((may_alias));

#define EMB    1024
#define NHEAD  16
#define HD     64
#define SEQ    2048
#define NBATCH 2
#define ROWS   (NBATCH*SEQ)   // 4096

__device__ __forceinline__ u16 f2b(float f) {
  uint32_t u; __builtin_memcpy(&u, &f, 4);
  u = u + 0x7fffu + ((u >> 16) & 1u);
  return (u16)(u >> 16);
}
__device__ __forceinline__ u16x8 ld8(const u16* p) { return *(const u16x8_ma*)p; }
__device__ __forceinline__ void  st8(u16* p, u16x8 v) { *(u16x8_ma*)p = v; }
__device__ __forceinline__ bf16x8 asbf(u16x8 v) {
  union { u16x8 u; bf16x8 b; } c; c.u = v; return c.b;
}
// packed f32x2 -> bf16x2 (RNE), T12 recipe (no builtin on gfx950)
__device__ __forceinline__ uint32_t cvtpk(float a, float b) {
  uint32_t r;
  asm("v_cvt_pk_bf16_f32 %0, %1, %2" : "=v"(r) : "v"(a), "v"(b));
  return r;
}
// async global->LDS, 16B/lane; LDS dest = wave-uniform base + lane*16 (m97).
__device__ __forceinline__ void async_cp16(const u16* g, u16* l) {
  __builtin_amdgcn_global_load_lds(
      (const __attribute__((address_space(1))) void*)g,
      (__attribute__((address_space(3))) void*)l, 16, 0, 0);
}

// ---------------------------------------------------------------------------
// Fused f32 -> bf16 conversion: x (4096 blocks) + 4 weights (1024 each).
// ---------------------------------------------------------------------------
__global__ __launch_bounds__(256) void cvt_all(
    const float* __restrict__ x,
    const float* __restrict__ w0, const float* __restrict__ w1,
    const float* __restrict__ w2, const float* __restrict__ w3,
    u16* __restrict__ xd, u16* __restrict__ d0, u16* __restrict__ d1,
    u16* __restrict__ d2, u16* __restrict__ d3)
{
  int bid = blockIdx.x;
  const float* s; u16* d; int off;
  if (bid < 4096) { s = x; d = xd; off = bid; }
  else {
    int t = bid - 4096; int m = t >> 10; off = t & 1023;
    switch (m) {
      case 0: s = w0; d = d0; break;
      case 1: s = w1; d = d1; break;
      case 2: s = w2; d = d2; break;
      default: s = w3; d = d3; break;
    }
  }
  size_t i = ((size_t)off * 256 + threadIdx.x) * 4;
  f32x4 v = *(const f32x4_ma*)(s + i);
  u16x4 o;
  #pragma unroll
  for (int j = 0; j < 4; j++) o[j] = f2b(v[j]);
  *(u16x4*)(d + i) = o;
}

// ---------------------------------------------------------------------------
// 128x128 GEMM core, BK=64 via dual 128x32 panels (each panel is the exact
// m97 layout, so the async_cp16 wave-uniform constraint and the measured
// bank behavior are preserved). 8 async + 32 MFMA per barrier pair, 16 iters.
// AMODE=0: A row-major. AMODE=1: A in [N,16,L,64]. B n-major.
// ---------------------------------------------------------------------------
template<int AMODE>
__device__ __forceinline__ void gemm_acc_128x128(
    const u16* __restrict__ A, const u16* __restrict__ B,
    int m0, int n0, u16* As, u16* Bs, f32x4 acc[4][4])
{
  const int tid  = threadIdx.x;
  const int lane = tid & 63;
  const int wave = tid >> 6;
  const int wm   = (wave >> 1) * 64;
  const int wn   = (wave & 1) * 64;
  const int ar   = tid >> 2;        // 0..63
  const int ac   = (tid & 3) * 8;   // 0,8,16,24
  const int lm   = lane & 15;
  const int lk   = (lane >> 4) * 8;

  #pragma unroll
  for (int i = 0; i < 4; i++)
    #pragma unroll
    for (int j = 0; j < 4; j++)
      #pragma unroll
      for (int e = 0; e < 4; e++) acc[i][j][e] = 0.f;

  for (int k0 = 0; k0 < EMB; k0 += 64) {
    size_t a0[2], a1[2];
    #pragma unroll
    for (int pnl = 0; pnl < 2; pnl++) {
      int kc = k0 + pnl * 32 + ac;
      if (AMODE == 0) {
        a0[pnl] = (size_t)(m0 + ar)      * EMB + kc;
        a1[pnl] = (size_t)(m0 + ar + 64) * EMB + kc;
      } else {
        int h = kc >> 6, d = kc & 63;
        int r0 = m0 + ar, r1 = m0 + ar + 64;
        a0[pnl] = (((size_t)((r0 >> 11) * NHEAD + h)) * SEQ + (r0 & (SEQ-1))) * HD + d;
        a1[pnl] = (((size_t)((r1 >> 11) * NHEAD + h)) * SEQ + (r1 & (SEQ-1))) * HD + d;
      }
    }
    __syncthreads();   // previous iteration's LDS reads complete
    #pragma unroll
    for (int pnl = 0; pnl < 2; pnl++) {
      const int pb = pnl * 4096;   // panel base (elems)
      async_cp16(A + a0[pnl], As + pb + tid * 8);
      async_cp16(A + a1[pnl], As + pb + (tid + 256) * 8);
      async_cp16(B + (size_t)(n0 + ar)      * EMB + k0 + pnl * 32 + ac, Bs + pb + tid * 8);
      async_cp16(B + (size_t)(n0 + ar + 64) * EMB + k0 + pnl * 32 + ac, Bs + pb + (tid + 256) * 8);
    }
    __syncthreads();   // drains vmcnt: both panels ready

    #pragma unroll
    for (int pnl = 0; pnl < 2; pnl++) {
      const int pb = pnl * 4096;
      bf16x8 af[4], bfr[4];
      #pragma unroll
      for (int i = 0; i < 4; i++)
        af[i] = asbf(ld8(As + pb + (wm + i * 16 + lm) * 32 + lk));
      #pragma unroll
      for (int j = 0; j < 4; j++)
        bfr[j] = asbf(ld8(Bs + pb + (wn + j * 16 + lm) * 32 + lk));
      #pragma unroll
      for (int i = 0; i < 4; i++)
        #pragma unroll
        for (int j = 0; j < 4; j++)
          acc[i][j] = __builtin_amdgcn_mfma_f32_16x16x32_bf16(af[i], bfr[j], acc[i][j], 0, 0, 0);
    }
  }
}

// LN over the wave's 64-col head span + scatter to bf16 [N, Hdst, L, 64].
__device__ __forceinline__ void epilogue_scatter_ln(
    f32x4 acc[4][4], u16* dst, int m0, int n0, int head_base, int Hdst,
    const float* g, const float* b, int do_ln)
{
  const int lane = threadIdx.x & 63, wave = threadIdx.x >> 6;
  const int wm = (wave >> 1) * 64, wn = (wave & 1) * 64;
  const int lm = lane & 15, quad = lane >> 4;

  float gv[4], bv[4];
  #pragma unroll
  for (int j = 0; j < 4; j++) { gv[j] = g[j * 16 + lm]; bv[j] = b[j * 16 + lm]; }

  #pragma unroll
  for (int i = 0; i < 4; i++)
    #pragma unroll
    for (int r = 0; r < 4; r++) {
      float val[4];
      #pragma unroll
      for (int j = 0; j < 4; j++) val[j] = acc[i][j][r];
      if (do_ln) {
        float s = val[0] + val[1] + val[2] + val[3];
        #pragma unroll
        for (int o = 8; o >= 1; o >>= 1) s += __shfl_xor(s, o, 64);
        float mean = s * (1.f / 64.f);
        float ss = 0.f;
        #pragma unroll
        for (int j = 0; j < 4; j++) { val[j] -= mean; ss += val[j] * val[j]; }
        #pragma unroll
        for (int o = 8; o >= 1; o >>= 1) ss += __shfl_xor(ss, o, 64);
        float inv = rsqrtf(ss * (1.f / 64.f) + 1e-5f);
        #pragma unroll
        for (int j = 0; j < 4; j++) val[j] = val[j] * inv * gv[j] + bv[j];
      }
      int row = m0 + wm + i * 16 + quad * 4 + r;
      int bn = row >> 11, l = row & (SEQ - 1);
      #pragma unroll
      for (int j = 0; j < 4; j++) {
        int col = n0 + wn + j * 16 + lm;
        int hl = (col >> 6) - head_base, d = col & 63;
        dst[(((size_t)(bn * Hdst + hl)) * SEQ + l) * HD + d] = f2b(val[j]);
      }
    }
}

// Merged QKV projection: grid (8, 32, 3).
__global__ __launch_bounds__(256) void gemm_qkv(
    const u16* __restrict__ x,
    const u16* __restrict__ Wq, const u16* __restrict__ Wk, const u16* __restrict__ Wv,
    const float* __restrict__ gq, const float* __restrict__ bq,
    const float* __restrict__ gk, const float* __restrict__ bk,
    u16* __restrict__ qd, u16* __restrict__ kb, u16* __restrict__ vb)
{
  __shared__ __align__(16) u16 As[128 * 64];
  __shared__ __align__(16) u16 Bs[128 * 64];
  const u16* W; u16* dst; const float* g; const float* b; int ln;
  if (blockIdx.z == 0)      { W = Wq; dst = qd; g = gq; b = bq; ln = 1; }
  else if (blockIdx.z == 1) { W = Wk; dst = kb; g = gk; b = bk; ln = 1; }
  else                      { W = Wv; dst = vb; g = gq; b = bq; ln = 0; }
  const int m0 = blockIdx.y * 128, n0 = blockIdx.x * 128;
  f32x4 acc[4][4];
  gemm_acc_128x128<0>(x, W, m0, n0, As, Bs, acc);
  epilogue_scatter_ln(acc, dst, m0, n0, 0, NHEAD, g, b, ln);
}

// Fallback kernels for small-workspace multi-pass K/V.
__global__ __launch_bounds__(256) void gemm_q(
    const u16* __restrict__ x, const u16* __restrict__ Wq,
    const float* __restrict__ gq, const float* __restrict__ bq,
    u16* __restrict__ qd)
{
  __shared__ __align__(16) u16 As[128 * 64];
  __shared__ __align__(16) u16 Bs[128 * 64];
  const int m0 = blockIdx.y * 128, n0 = blockIdx.x * 128;
  f32x4 acc[4][4];
  gemm_acc_128x128<0>(x, Wq, m0, n0, As, Bs, acc);
  epilogue_scatter_ln(acc, qd, m0, n0, 0, NHEAD, gq, bq, 1);
}
__global__ __launch_bounds__(256) void gemm_kv(
    const u16* __restrict__ x,
    const u16* __restrict__ Wk, const u16* __restrict__ Wv,
    const float* __restrict__ gk, const float* __restrict__ bk,
    u16* __restrict__ k, u16* __restrict__ v, int head_lo, int hpp)
{
  __shared__ __align__(16) u16 As[128 * 64];
  __shared__ __align__(16) u16 Bs[128 * 64];
  const int m0 = blockIdx.y * 128, n0 = blockIdx.x * 128;
  const u16* W = (blockIdx.z == 0 ? Wk : Wv) + (size_t)head_lo * HD * EMB;
  u16* dst = (blockIdx.z == 0) ? k : v;
  f32x4 acc[4][4];
  gemm_acc_128x128<0>(x, W, m0, n0, As, Bs, acc);
  epilogue_scatter_ln(acc, dst, m0, n0, 0, hpp, gk, bk, blockIdx.z == 0);
}

// ---------------------------------------------------------------------------
// Flash causal attention, swapped-QK^T, in-register softmax, K UN-STAGED.
// grid (32, hpp, NBATCH), block 256; one 64-row q-tile per block.
//
// K is NOT staged in LDS (per-head K = 256 KB, L2-resident; 32 blocks/head
// + 4 waves/block re-read the same lines -> L1/L2 broadcast; m169
// precedent). The swapped-QK A-fragment is 8 contiguous bf16 per lane, so
// kf[ks][j] is loaded straight from global in fragment layout
// (global_load_dwordx4, 16 rows x 64B segments/wave). kf for tile t+1 is
// issued right AFTER the QK MFMAs consume tile t (full softmax+PV+barrier
// of latency cover, no extra buffer regs).
// This removes the 8 ds_read_b128/wave-iter that were ~8-way bank
// conflicted with SATT=72 (the 10.8M SQ_LDS_BANK_CONFLICT source) plus the
// K ds_writes; LDS drops to 16 KiB (Vts only).
// ---------------------------------------------------------------------------
__global__ __launch_bounds__(256, 4) void attn(
    u16* qd, const u16* __restrict__ K, const u16* __restrict__ V,
    int head_lo, int hpp)
{
  __shared__ __align__(16) u16 Vts[2][64 * 64];     // XOR-swizzled transpose

  const int hl = blockIdx.y, n = blockIdx.z;
  const int p = (7 * blockIdx.x + hl + 16 * n) & 31;   // scrambled q-tile id
  const int tid = threadIdx.x, lane = tid & 63, wave = tid >> 6;
  const int lm = lane & 15, quad = lane >> 4, lk = quad * 8;
  u16* Qh = qd + ((size_t)(n * NHEAD + head_lo + hl)) * SEQ * HD;
  const u16* Kh = K + ((size_t)(n * hpp + hl)) * SEQ * HD;
  const u16* Vh = V + ((size_t)(n * hpp + hl)) * SEQ * HD;

  const int sr = tid >> 3;        // 0..31 (key)
  const int sc = (tid & 7) * 8;   // 0..56 (d base)
  const int vswz = tid & 7;

  // Q fragment (B-operand of swapped QK^T): rows p*64 + wave*16 + lm
  bf16x8 aq[2];
  #pragma unroll
  for (int ks = 0; ks < 2; ++ks)
    aq[ks] = asbf(ld8(Qh + (size_t)(p * 64 + wave * 16 + lm) * HD + ks * 32 + lk));

  // K fragments for tile 0, loaded directly from global in MFMA layout.
  bf16x8 kf[2][4];
  #pragma unroll
  for (int ks = 0; ks < 2; ++ks)
    #pragma unroll
    for (int j = 0; j < 4; ++j)
      kf[ks][j] = asbf(ld8(Kh + (size_t)(j * 16 + lm) * HD + ks * 32 + lk));

  // V staging: tile 0 -> LDS (swizzled transpose), tile 1 -> regs.
  u16x8 vr0, vr1;
  vr0 = ld8(Vh + (size_t)(sr)      * HD + sc);
  vr1 = ld8(Vh + (size_t)(sr + 32) * HD + sc);
  #pragma unroll
  for (int jj = 0; jj < 8; jj++) {
    int d = sc + jj;
    Vts[0][d * 64 + (((sr >> 3) ^ vswz) * 8) + (sr & 7)]        = vr0[jj];
    Vts[0][d * 64 + ((((sr + 32) >> 3) ^ vswz) * 8) + (sr & 7)] = vr1[jj];
  }
  vr0 = ld8(Vh + (size_t)(64 + sr)      * HD + sc);
  vr1 = ld8(Vh + (size_t)(64 + sr + 32) * HD + sc);
  __syncthreads();

  f32x4 oacc[4];
  #pragma unroll
  for (int j = 0; j < 4; j++)
    #pragma unroll
    for (int e = 0; e < 4; e++) oacc[j][e] = 0.f;
  float m_i = -1e30f, psum = 0.f;

  const int idx0 = (((quad & 1) * 2) * 16 + lm) * 4;   // bpermute byte idx, w<2
  const int idx1 = idx0 + 64;                          // w>=2 (qq+1)
  const int qrow = p * 64 + wave * 16 + lm;

  for (int t = 0; t <= p; ++t) {
    const int cur = t & 1;
    if (t < p) {
      const int nb = 1 - cur;
      #pragma unroll
      for (int jj = 0; jj < 8; jj++) {
        int d = sc + jj;
        Vts[nb][d * 64 + (((sr >> 3) ^ vswz) * 8) + (sr & 7)]        = vr0[jj];
        Vts[nb][d * 64 + ((((sr + 32) >> 3) ^ vswz) * 8) + (sr & 7)] = vr1[jj];
      }
      if (t + 1 < p) {
        const size_t base = (size_t)(t + 2) * 64;
        vr0 = ld8(Vh + (base + sr)      * HD + sc);
        vr1 = ld8(Vh + (base + sr + 32) * HD + sc);
      }
    }

    // S^T: s[j][r] = S[q=qrow][key = t*64 + j*16 + quad*4 + r]
    f32x4 s[4];
    #pragma unroll
    for (int j = 0; j < 4; j++)
      #pragma unroll
      for (int e = 0; e < 4; e++) s[j][e] = 0.f;
    __builtin_amdgcn_s_setprio(1);
    #pragma unroll
    for (int ks = 0; ks < 2; ++ks)
      #pragma unroll
      for (int j = 0; j < 4; j++)
        s[j] = __builtin_amdgcn_mfma_f32_16x16x32_bf16(kf[ks][j], aq[ks], s[j], 0, 0, 0);
    __builtin_amdgcn_s_setprio(0);

    // refill kf with tile t+1 (regs just freed by the MFMAs above; the
    // next use is after softmax+PV+barrier -> latency fully covered).
    if (t < p) {
      const u16* Kt = Kh + (size_t)(t + 1) * 64 * HD;
      #pragma unroll
      for (int ks = 0; ks < 2; ++ks)
        #pragma unroll
        for (int j = 0; j < 4; ++j)
          kf[ks][j] = asbf(ld8(Kt + (size_t)(j * 16 + lm) * HD + ks * 32 + lk));
    }

    if (t == p) {   // causal mask on the diagonal tile
      #pragma unroll
      for (int j = 0; j < 4; j++)
        #pragma unroll
        for (int r = 0; r < 4; r++)
          if (t * 64 + j * 16 + quad * 4 + r > qrow) s[j][r] = -1e30f;
    }

    // row max: 15 local fmax + cross-quad butterfly (2 shfl)
    float mx = fmaxf(fmaxf(s[0][0], s[0][1]), fmaxf(s[0][2], s[0][3]));
    #pragma unroll
    for (int j = 1; j < 4; j++)
      mx = fmaxf(mx, fmaxf(fmaxf(s[j][0], s[j][1]), fmaxf(s[j][2], s[j][3])));
    mx = fmaxf(mx, __shfl_xor(mx, 16, 64));
    mx = fmaxf(mx, __shfl_xor(mx, 32, 64));
    const float mnew = fmaxf(m_i, mx);
    const float alpha = __expf(m_i - mnew);
    m_i = mnew;
    float part = 0.f;
    #pragma unroll
    for (int j = 0; j < 4; j++)
      #pragma unroll
      for (int r = 0; r < 4; r++) {
        float pv = __expf(s[j][r] - mnew);
        s[j][r] = pv;
        part += pv;
      }
    psum = psum * alpha + part;

    // rescale O rows (O rows are quad*4+r; alpha lives at row lm -> gather)
    float ar_[4];
    #pragma unroll
    for (int r = 0; r < 4; r++)
      ar_[r] = __shfl(alpha, (lane & 48) | (quad * 4 + r), 64);
    #pragma unroll
    for (int j = 0; j < 4; j++)
      #pragma unroll
      for (int r = 0; r < 4; r++) oacc[j][r] *= ar_[r];

    // pack P pairs: u[2j]=keys(j*16+quad*4+{0,1}), u[2j+1]={2,3}
    uint32_t u[8];
    #pragma unroll
    for (int j = 0; j < 4; j++) {
      u[2 * j]     = cvtpk(s[j][0], s[j][1]);
      u[2 * j + 1] = cvtpk(s[j][2], s[j][3]);
    }

    __builtin_amdgcn_s_setprio(1);
    #pragma unroll
    for (int ks = 0; ks < 2; ++ks) {
      union { uint32_t w[4]; bf16x8 v; } cv;
      #pragma unroll
      for (int w = 0; w < 4; w++) {
        int lo = __builtin_amdgcn_ds_bpermute(w < 2 ? idx0 : idx1,
                                              (int)u[ks * 4 + (w & 1)]);
        int hi = __builtin_amdgcn_ds_bpermute(w < 2 ? idx0 : idx1,
                                              (int)u[ks * 4 + 2 + (w & 1)]);
        cv.w[w] = (quad < 2) ? (uint32_t)lo : (uint32_t)hi;
      }
      bf16x8 ap = cv.v;   // A-frag: P[q=lm][keys ks*32+quad*8 .. +7]
      #pragma unroll
      for (int j = 0; j < 4; j++) {
        int dg = 2 * j + (lm >> 3);
        int g  = (ks * 4 + quad) ^ (dg & 7);
        bf16x8 bv = asbf(ld8(&Vts[cur][(j * 16 + lm) * 64 + g * 8]));
        oacc[j] = __builtin_amdgcn_mfma_f32_16x16x32_bf16(ap, bv, oacc[j], 0, 0, 0);
      }
    }
    __builtin_amdgcn_s_setprio(0);
    __syncthreads();   // single per-iteration barrier (dbuf swap)
  }

  // epilogue: row sum lives at row lm; gather inv to O rows quad*4+r
  float s_ = psum;
  s_ += __shfl_xor(s_, 16, 64);
  s_ += __shfl_xor(s_, 32, 64);
  const float inv = 1.0f / s_;
  float ir_[4];
  #pragma unroll
  for (int r = 0; r < 4; r++)
    ir_[r] = __shfl(inv, (lane & 48) | (quad * 4 + r), 64);
  #pragma unroll
  for (int r = 0; r < 4; r++) {
    const int row = p * 64 + wave * 16 + quad * 4 + r;
    #pragma unroll
    for (int j = 0; j < 4; j++)
      Qh[(size_t)row * HD + j * 16 + lm] = f2b(oacc[j][r] * ir_[r]);
  }
}

// ---------------------------------------------------------------------------
// Output projection, 64x128 tiles, BK=64 dual-panel: grid (8, 64).
// d_out(f32) = ao @ Wo^T + bo ; ao in [N,16,L,64] bf16.
// ---------------------------------------------------------------------------
__global__ __launch_bounds__(256) void gemm_out(
    const u16* __restrict__ ao, const u16* __restrict__ Wo,
    const float* __restrict__ bo, float* __restrict__ out)
{
  __shared__ __align__(16) u16 As[64 * 64];    // 2 panels of 64x32
  __shared__ __align__(16) u16 Bs[128 * 64];   // 2 panels of 128x32
  const int m0 = blockIdx.y * 64, n0 = blockIdx.x * 128;
  const int tid  = threadIdx.x;
  const int lane = tid & 63;
  const int wave = tid >> 6;
  const int wm   = (wave >> 1) * 32;
  const int wn   = (wave & 1) * 64;
  const int ar   = tid >> 2;        // 0..63
  const int ac   = (tid & 3) * 8;
  const int lm   = lane & 15;
  const int lk   = (lane >> 4) * 8;

  f32x4 acc[2][4];
  #pragma unroll
  for (int i = 0; i < 2; i++)
    #pragma unroll
    for (int j = 0; j < 4; j++)
      #pragma unroll
      for (int e = 0; e < 4; e++) acc[i][j][e] = 0.f;

  for (int k0 = 0; k0 < EMB; k0 += 64) {
    size_t aoff[2];
    #pragma unroll
    for (int pnl = 0; pnl < 2; pnl++) {
      int kc = k0 + pnl * 32 + ac, h = kc >> 6, d = kc & 63;
      int r0 = m0 + ar;
      aoff[pnl] = (((size_t)((r0 >> 11) * NHEAD + h)) * SEQ + (r0 & (SEQ-1))) * HD + d;
    }
    __syncthreads();
    #pragma unroll
    for (int pnl = 0; pnl < 2; pnl++) {
      async_cp16(ao + aoff[pnl], As + pnl * 2048 + tid * 8);
      async_cp16(Wo + (size_t)(n0 + ar)      * EMB + k0 + pnl * 32 + ac, Bs + pnl * 4096 + tid * 8);
      async_cp16(Wo + (size_t)(n0 + ar + 64) * EMB + k0 + pnl * 32 + ac, Bs + pnl * 4096 + (tid + 256) * 8);
    }
    __syncthreads();

    #pragma unroll
    for (int pnl = 0; pnl < 2; pnl++) {
      bf16x8 af[2], bfr[4];
      #pragma unroll
      for (int i = 0; i < 2; i++)
        af[i] = asbf(ld8(As + pnl * 2048 + (wm + i * 16 + lm) * 32 + lk));
      #pragma unroll
      for (int j = 0; j < 4; j++)
        bfr[j] = asbf(ld8(Bs + pnl * 4096 + (wn + j * 16 + lm) * 32 + lk));
      #pragma unroll
      for (int i = 0; i < 2; i++)
        #pragma unroll
        for (int j = 0; j < 4; j++)
          acc[i][j] = __builtin_amdgcn_mfma_f32_16x16x32_bf16(af[i], bfr[j], acc[i][j], 0, 0, 0);
    }
  }

  const int quad = lane >> 4;
  #pragma unroll
  for (int j = 0; j < 4; j++) {
    int col = n0 + wn + j * 16 + lm;
    float bias = bo[col];
    #pragma unroll
    for (int i = 0; i < 2; i++)
      #pragma unroll
      for (int r = 0; r < 4; r++) {
        int row = m0 + wm + i * 16 + quad * 4 + r;
        out[(size_t)row * EMB + col] = acc[i][j][r] + bias;
      }
  }
}

extern "C" void kernel_launch(void* const* d_in, const int* in_sizes, int n_in,
                              void* d_out, int out_size, void* d_ws, size_t ws_size,
                              hipStream_t stream)
{
  const float* xf  = (const float*)d_in[0];
  const float* Wqf = (const float*)d_in[2];
  const float* Wkf = (const float*)d_in[3];
  const float* Wvf = (const float*)d_in[4];
  const float* gq  = (const float*)d_in[5];
  const float* bq  = (const float*)d_in[6];
  const float* gk  = (const float*)d_in[7];
  const float* bk  = (const float*)d_in[8];
  const float* Wof = (const float*)d_in[9];
  const float* bo  = (const float*)d_in[10];

  const size_t MB = 1u << 20;
  u16* xb  = (u16*)d_ws;                           // 8 MiB
  u16* wqb = xb  + (size_t)ROWS * EMB;             // 2 MiB each
  u16* wkb = wqb + (size_t)EMB * EMB;
  u16* wvb = wkb + (size_t)EMB * EMB;
  u16* wob = wvb + (size_t)EMB * EMB;
  u16* kvbase = wob + (size_t)EMB * EMB;           // ws + 16 MiB

  size_t avail = (ws_size > 16 * MB) ? ws_size - 16 * MB : 2 * MB;
  int hpp = NHEAD;
  while ((size_t)hpp * MB > avail && hpp > 2) hpp >>= 1;
  const size_t kv_elems = (size_t)hpp * NBATCH * SEQ * HD;
  u16* kbuf = kvbase;
  u16* vbuf = kbuf + kv_elems;

  // Q (bf16, + in-place attn output) lives in the x input buffer (dead
  // after cvt_all). gemm_out writes f32 straight to d_out.
  u16* qd = (u16*)d_in[0];
  float* out = (float*)d_out;

  cvt_all<<<dim3(8192), 256, 0, stream>>>(xf, Wqf, Wkf, Wvf, Wof,
                                          xb, wqb, wkb, wvb, wob);
  if (hpp == NHEAD) {
    gemm_qkv<<<dim3(8, 32, 3), 256, 0, stream>>>(xb, wqb, wkb, wvb,
                                                 gq, bq, gk, bk,
                                                 qd, kbuf, vbuf);
    attn<<<dim3(32, NHEAD, NBATCH), 256, 0, stream>>>(qd, kbuf, vbuf, 0, NHEAD);
  } else {
    gemm_q<<<dim3(8, 32), 256, 0, stream>>>(xb, wqb, gq, bq, qd);
    for (int g = 0; g < NHEAD / hpp; ++g) {
      gemm_kv<<<dim3(hpp / 2, 32, 2), 256, 0, stream>>>(xb, wkb, wvb, gk, bk,
                                                        kbuf, vbuf, g * hpp, hpp);
      attn<<<dim3(32, hpp, NBATCH), 256, 0, stream>>>(qd, kbuf, vbuf, g * hpp, hpp);
    }
  }
  gemm_out<<<dim3(8, 64), 256, 0, stream>>>(qd, wob, bo, out);
}

// Round 3
// 217.516 us; speedup vs baseline: 1.1601x; 1.1601x over previous
//
#include <hip/hip_runtime.h>
#include <stdint.h>

typedef unsigned short u16;
typedef u16   u16x4    __attribute__((ext_vector_type(4)));
typedef u16   u16x8    __attribute__((ext_vector_type(8)));
typedef u16x8 u16x8_ma __attribute__((may_alias));
typedef __bf16 bf16x8  __attribute__((ext_vector_type(8)));
typedef float f32x4    __attribute__((ext_vector_type(4)));
typedef f32x4 f32x4_ma __attribute__((may_alias));

#define EMB    1024
#define NHEAD  16
#define HD     64
#define SEQ    2048
#define NBATCH 2
#define ROWS   (NBATCH*SEQ)   // 4096
#define SATT   72             // attn K LDS row stride (balanced 8x4-bank groups)

__device__ __forceinline__ u16 f2b(float f) {
  uint32_t u; __builtin_memcpy(&u, &f, 4);
  u = u + 0x7fffu + ((u >> 16) & 1u);
  return (u16)(u >> 16);
}
__device__ __forceinline__ u16x8 ld8(const u16* p) { return *(const u16x8_ma*)p; }
__device__ __forceinline__ void  st8(u16* p, u16x8 v) { *(u16x8_ma*)p = v; }
__device__ __forceinline__ bf16x8 asbf(u16x8 v) {
  union { u16x8 u; bf16x8 b; } c; c.u = v; return c.b;
}
// packed f32x2 -> bf16x2 (RNE), T12 recipe (no builtin on gfx950)
__device__ __forceinline__ uint32_t cvtpk(float a, float b) {
  uint32_t r;
  asm("v_cvt_pk_bf16_f32 %0, %1, %2" : "=v"(r) : "v"(a), "v"(b));
  return r;
}
// async global->LDS, 16B/lane; LDS dest = wave-uniform base + lane*16 (m97).
__device__ __forceinline__ void async_cp16(const u16* g, u16* l) {
  __builtin_amdgcn_global_load_lds(
      (const __attribute__((address_space(1))) void*)g,
      (__attribute__((address_space(3))) void*)l, 16, 0, 0);
}

// ---------------------------------------------------------------------------
// Fused f32 -> bf16 conversion: x (4096 blocks) + 4 weights (1024 each).
// ---------------------------------------------------------------------------
__global__ __launch_bounds__(256) void cvt_all(
    const float* __restrict__ x,
    const float* __restrict__ w0, const float* __restrict__ w1,
    const float* __restrict__ w2, const float* __restrict__ w3,
    u16* __restrict__ xd, u16* __restrict__ d0, u16* __restrict__ d1,
    u16* __restrict__ d2, u16* __restrict__ d3)
{
  int bid = blockIdx.x;
  const float* s; u16* d; int off;
  if (bid < 4096) { s = x; d = xd; off = bid; }
  else {
    int t = bid - 4096; int m = t >> 10; off = t & 1023;
    switch (m) {
      case 0: s = w0; d = d0; break;
      case 1: s = w1; d = d1; break;
      case 2: s = w2; d = d2; break;
      default: s = w3; d = d3; break;
    }
  }
  size_t i = ((size_t)off * 256 + threadIdx.x) * 4;
  f32x4 v = *(const f32x4_ma*)(s + i);
  u16x4 o;
  #pragma unroll
  for (int j = 0; j < 4; j++) o[j] = f2b(v[j]);
  *(u16x4*)(d + i) = o;
}

// ---------------------------------------------------------------------------
// 128x128 GEMM core, BK=64 via dual 128x32 panels (each panel is the exact
// m97 layout, so the async_cp16 wave-uniform constraint and the measured
// bank behavior are preserved). 8 async + 32 MFMA per barrier pair, 16 iters.
// AMODE=0: A row-major. AMODE=1: A in [N,16,L,64]. B n-major.
// ---------------------------------------------------------------------------
template<int AMODE>
__device__ __forceinline__ void gemm_acc_128x128(
    const u16* __restrict__ A, const u16* __restrict__ B,
    int m0, int n0, u16* As, u16* Bs, f32x4 acc[4][4])
{
  const int tid  = threadIdx.x;
  const int lane = tid & 63;
  const int wave = tid >> 6;
  const int wm   = (wave >> 1) * 64;
  const int wn   = (wave & 1) * 64;
  const int ar   = tid >> 2;        // 0..63
  const int ac   = (tid & 3) * 8;   // 0,8,16,24
  const int lm   = lane & 15;
  const int lk   = (lane >> 4) * 8;

  #pragma unroll
  for (int i = 0; i < 4; i++)
    #pragma unroll
    for (int j = 0; j < 4; j++)
      #pragma unroll
      for (int e = 0; e < 4; e++) acc[i][j][e] = 0.f;

  for (int k0 = 0; k0 < EMB; k0 += 64) {
    size_t a0[2], a1[2];
    #pragma unroll
    for (int pnl = 0; pnl < 2; pnl++) {
      int kc = k0 + pnl * 32 + ac;
      if (AMODE == 0) {
        a0[pnl] = (size_t)(m0 + ar)      * EMB + kc;
        a1[pnl] = (size_t)(m0 + ar + 64) * EMB + kc;
      } else {
        int h = kc >> 6, d = kc & 63;
        int r0 = m0 + ar, r1 = m0 + ar + 64;
        a0[pnl] = (((size_t)((r0 >> 11) * NHEAD + h)) * SEQ + (r0 & (SEQ-1))) * HD + d;
        a1[pnl] = (((size_t)((r1 >> 11) * NHEAD + h)) * SEQ + (r1 & (SEQ-1))) * HD + d;
      }
    }
    __syncthreads();   // previous iteration's LDS reads complete
    #pragma unroll
    for (int pnl = 0; pnl < 2; pnl++) {
      const int pb = pnl * 4096;   // panel base (elems)
      async_cp16(A + a0[pnl], As + pb + tid * 8);
      async_cp16(A + a1[pnl], As + pb + (tid + 256) * 8);
      async_cp16(B + (size_t)(n0 + ar)      * EMB + k0 + pnl * 32 + ac, Bs + pb + tid * 8);
      async_cp16(B + (size_t)(n0 + ar + 64) * EMB + k0 + pnl * 32 + ac, Bs + pb + (tid + 256) * 8);
    }
    __syncthreads();   // drains vmcnt: both panels ready

    #pragma unroll
    for (int pnl = 0; pnl < 2; pnl++) {
      const int pb = pnl * 4096;
      bf16x8 af[4], bfr[4];
      #pragma unroll
      for (int i = 0; i < 4; i++)
        af[i] = asbf(ld8(As + pb + (wm + i * 16 + lm) * 32 + lk));
      #pragma unroll
      for (int j = 0; j < 4; j++)
        bfr[j] = asbf(ld8(Bs + pb + (wn + j * 16 + lm) * 32 + lk));
      #pragma unroll
      for (int i = 0; i < 4; i++)
        #pragma unroll
        for (int j = 0; j < 4; j++)
          acc[i][j] = __builtin_amdgcn_mfma_f32_16x16x32_bf16(af[i], bfr[j], acc[i][j], 0, 0, 0);
    }
  }
}

// LN over the wave's 64-col head span + scatter to bf16 [N, Hdst, L, 64].
__device__ __forceinline__ void epilogue_scatter_ln(
    f32x4 acc[4][4], u16* dst, int m0, int n0, int head_base, int Hdst,
    const float* g, const float* b, int do_ln)
{
  const int lane = threadIdx.x & 63, wave = threadIdx.x >> 6;
  const int wm = (wave >> 1) * 64, wn = (wave & 1) * 64;
  const int lm = lane & 15, quad = lane >> 4;

  float gv[4], bv[4];
  #pragma unroll
  for (int j = 0; j < 4; j++) { gv[j] = g[j * 16 + lm]; bv[j] = b[j * 16 + lm]; }

  #pragma unroll
  for (int i = 0; i < 4; i++)
    #pragma unroll
    for (int r = 0; r < 4; r++) {
      float val[4];
      #pragma unroll
      for (int j = 0; j < 4; j++) val[j] = acc[i][j][r];
      if (do_ln) {
        float s = val[0] + val[1] + val[2] + val[3];
        #pragma unroll
        for (int o = 8; o >= 1; o >>= 1) s += __shfl_xor(s, o, 64);
        float mean = s * (1.f / 64.f);
        float ss = 0.f;
        #pragma unroll
        for (int j = 0; j < 4; j++) { val[j] -= mean; ss += val[j] * val[j]; }
        #pragma unroll
        for (int o = 8; o >= 1; o >>= 1) ss += __shfl_xor(ss, o, 64);
        float inv = rsqrtf(ss * (1.f / 64.f) + 1e-5f);
        #pragma unroll
        for (int j = 0; j < 4; j++) val[j] = val[j] * inv * gv[j] + bv[j];
      }
      int row = m0 + wm + i * 16 + quad * 4 + r;
      int bn = row >> 11, l = row & (SEQ - 1);
      #pragma unroll
      for (int j = 0; j < 4; j++) {
        int col = n0 + wn + j * 16 + lm;
        int hl = (col >> 6) - head_base, d = col & 63;
        dst[(((size_t)(bn * Hdst + hl)) * SEQ + l) * HD + d] = f2b(val[j]);
      }
    }
}

// Merged QKV projection: grid (8, 32, 3).
__global__ __launch_bounds__(256) void gemm_qkv(
    const u16* __restrict__ x,
    const u16* __restrict__ Wq, const u16* __restrict__ Wk, const u16* __restrict__ Wv,
    const float* __restrict__ gq, const float* __restrict__ bq,
    const float* __restrict__ gk, const float* __restrict__ bk,
    u16* __restrict__ qd, u16* __restrict__ kb, u16* __restrict__ vb)
{
  __shared__ __align__(16) u16 As[128 * 64];
  __shared__ __align__(16) u16 Bs[128 * 64];
  const u16* W; u16* dst; const float* g; const float* b; int ln;
  if (blockIdx.z == 0)      { W = Wq; dst = qd; g = gq; b = bq; ln = 1; }
  else if (blockIdx.z == 1) { W = Wk; dst = kb; g = gk; b = bk; ln = 1; }
  else                      { W = Wv; dst = vb; g = gq; b = bq; ln = 0; }
  const int m0 = blockIdx.y * 128, n0 = blockIdx.x * 128;
  f32x4 acc[4][4];
  gemm_acc_128x128<0>(x, W, m0, n0, As, Bs, acc);
  epilogue_scatter_ln(acc, dst, m0, n0, 0, NHEAD, g, b, ln);
}

// Fallback kernels for small-workspace multi-pass K/V.
__global__ __launch_bounds__(256) void gemm_q(
    const u16* __restrict__ x, const u16* __restrict__ Wq,
    const float* __restrict__ gq, const float* __restrict__ bq,
    u16* __restrict__ qd)
{
  __shared__ __align__(16) u16 As[128 * 64];
  __shared__ __align__(16) u16 Bs[128 * 64];
  const int m0 = blockIdx.y * 128, n0 = blockIdx.x * 128;
  f32x4 acc[4][4];
  gemm_acc_128x128<0>(x, Wq, m0, n0, As, Bs, acc);
  epilogue_scatter_ln(acc, qd, m0, n0, 0, NHEAD, gq, bq, 1);
}
__global__ __launch_bounds__(256) void gemm_kv(
    const u16* __restrict__ x,
    const u16* __restrict__ Wk, const u16* __restrict__ Wv,
    const float* __restrict__ gk, const float* __restrict__ bk,
    u16* __restrict__ k, u16* __restrict__ v, int head_lo, int hpp)
{
  __shared__ __align__(16) u16 As[128 * 64];
  __shared__ __align__(16) u16 Bs[128 * 64];
  const int m0 = blockIdx.y * 128, n0 = blockIdx.x * 128;
  const u16* W = (blockIdx.z == 0 ? Wk : Wv) + (size_t)head_lo * HD * EMB;
  u16* dst = (blockIdx.z == 0) ? k : v;
  f32x4 acc[4][4];
  gemm_acc_128x128<0>(x, W, m0, n0, As, Bs, acc);
  epilogue_scatter_ln(acc, dst, m0, n0, 0, hpp, gk, bk, blockIdx.z == 0);
}

// ---------------------------------------------------------------------------
// Flash causal attention, swapped-QK^T in-register-softmax (R1 structure,
// K back in LDS — the R2 global-fragment K loads serialized on L1/TA).
// grid (32, hpp, NBATCH), block 256; one 64-row q-tile per block.
//
// Load-balanced tile map: per-block work is p+1 tiles (32x spread). Under
// round-robin XCD dispatch at 4 blocks/CU, a CU's co-resident blocks are
// ~256 apart in linear block id (same bx, hl differing by 8, both n).
// Since 31-p == p^31, p = perm(bx, hl&7, n) ^ (31*(hl>>3)) makes each
// CU's 4 blocks sum to exactly 66 tile-iters (random scramble: mean 66,
// tail ~110 -> ~1.6x makespan penalty). Perf heuristic only.
// ---------------------------------------------------------------------------
__global__ __launch_bounds__(256, 4) void attn(
    u16* qd, const u16* __restrict__ K, const u16* __restrict__ V,
    int head_lo, int hpp)
{
  __shared__ __align__(16) u16 Ks[2][64 * SATT];
  __shared__ __align__(16) u16 Vts[2][64 * 64];     // XOR-swizzled transpose

  const int hl = blockIdx.y, n = blockIdx.z;
  const int perm = (7 * blockIdx.x + (hl & 7) + 8 * n) & 31;
  const int p = perm ^ (31 * (hl >> 3));            // complementary pairs
  const int tid = threadIdx.x, lane = tid & 63, wave = tid >> 6;
  const int lm = lane & 15, quad = lane >> 4, lk = quad * 8;
  u16* Qh = qd + ((size_t)(n * NHEAD + head_lo + hl)) * SEQ * HD;
  const u16* Kh = K + ((size_t)(n * hpp + hl)) * SEQ * HD;
  const u16* Vh = V + ((size_t)(n * hpp + hl)) * SEQ * HD;

  const int sr = tid >> 3;        // 0..31 (key)
  const int sc = (tid & 7) * 8;   // 0..56 (d base)
  const int vswz = tid & 7;

  // Q fragment (B-operand of swapped QK^T): rows p*64 + wave*16 + lm
  bf16x8 aq[2];
  #pragma unroll
  for (int ks = 0; ks < 2; ++ks)
    aq[ks] = asbf(ld8(Qh + (size_t)(p * 64 + wave * 16 + lm) * HD + ks * 32 + lk));

  u16x8 kr0, kr1, vr0, vr1;
  kr0 = ld8(Kh + (size_t)(sr)      * HD + sc);
  kr1 = ld8(Kh + (size_t)(sr + 32) * HD + sc);
  vr0 = ld8(Vh + (size_t)(sr)      * HD + sc);
  vr1 = ld8(Vh + (size_t)(sr + 32) * HD + sc);
  st8(&Ks[0][sr * SATT + sc], kr0);
  st8(&Ks[0][(sr + 32) * SATT + sc], kr1);
  #pragma unroll
  for (int jj = 0; jj < 8; jj++) {
    int d = sc + jj;
    Vts[0][d * 64 + (((sr >> 3) ^ vswz) * 8) + (sr & 7)]        = vr0[jj];
    Vts[0][d * 64 + ((((sr + 32) >> 3) ^ vswz) * 8) + (sr & 7)] = vr1[jj];
  }
  kr0 = ld8(Kh + (size_t)(64 + sr)      * HD + sc);
  kr1 = ld8(Kh + (size_t)(64 + sr + 32) * HD + sc);
  vr0 = ld8(Vh + (size_t)(64 + sr)      * HD + sc);
  vr1 = ld8(Vh + (size_t)(64 + sr + 32) * HD + sc);
  __syncthreads();

  f32x4 oacc[4];
  #pragma unroll
  for (int j = 0; j < 4; j++)
    #pragma unroll
    for (int e = 0; e < 4; e++) oacc[j][e] = 0.f;
  float m_i = -1e30f, psum = 0.f;

  const int idx0 = (((quad & 1) * 2) * 16 + lm) * 4;   // bpermute byte idx, w<2
  const int idx1 = idx0 + 64;                          // w>=2 (qq+1)
  const int qrow = p * 64 + wave * 16 + lm;

  for (int t = 0; t <= p; ++t) {
    const int cur = t & 1;
    if (t < p) {
      const int nb = 1 - cur;
      st8(&Ks[nb][sr * SATT + sc], kr0);
      st8(&Ks[nb][(sr + 32) * SATT + sc], kr1);
      #pragma unroll
      for (int jj = 0; jj < 8; jj++) {
        int d = sc + jj;
        Vts[nb][d * 64 + (((sr >> 3) ^ vswz) * 8) + (sr & 7)]        = vr0[jj];
        Vts[nb][d * 64 + ((((sr + 32) >> 3) ^ vswz) * 8) + (sr & 7)] = vr1[jj];
      }
      if (t + 1 < p) {
        const size_t base = (size_t)(t + 2) * 64;
        kr0 = ld8(Kh + (base + sr)      * HD + sc);
        kr1 = ld8(Kh + (base + sr + 32) * HD + sc);
        vr0 = ld8(Vh + (base + sr)      * HD + sc);
        vr1 = ld8(Vh + (base + sr + 32) * HD + sc);
      }
    }

    // S^T: s[j][r] = S[q=qrow][key = t*64 + j*16 + quad*4 + r]
    f32x4 s[4];
    #pragma unroll
    for (int j = 0; j < 4; j++)
      #pragma unroll
      for (int e = 0; e < 4; e++) s[j][e] = 0.f;
    __builtin_amdgcn_s_setprio(1);
    #pragma unroll
    for (int ks = 0; ks < 2; ++ks)
      #pragma unroll
      for (int j = 0; j < 4; j++) {
        bf16x8 ak = asbf(ld8(&Ks[cur][(j * 16 + lm) * SATT + ks * 32 + lk]));
        s[j] = __builtin_amdgcn_mfma_f32_16x16x32_bf16(ak, aq[ks], s[j], 0, 0, 0);
      }
    __builtin_amdgcn_s_setprio(0);

    if (t == p) {   // causal mask on the diagonal tile
      #pragma unroll
      for (int j = 0; j < 4; j++)
        #pragma unroll
        for (int r = 0; r < 4; r++)
          if (t * 64 + j * 16 + quad * 4 + r > qrow) s[j][r] = -1e30f;
    }

    // row max: 15 local fmax + cross-quad butterfly (2 shfl)
    float mx = fmaxf(fmaxf(s[0][0], s[0][1]), fmaxf(s[0][2], s[0][3]));
    #pragma unroll
    for (int j = 1; j < 4; j++)
      mx = fmaxf(mx, fmaxf(fmaxf(s[j][0], s[j][1]), fmaxf(s[j][2], s[j][3])));
    mx = fmaxf(mx, __shfl_xor(mx, 16, 64));
    mx = fmaxf(mx, __shfl_xor(mx, 32, 64));
    const float mnew = fmaxf(m_i, mx);
    const float alpha = __expf(m_i - mnew);
    m_i = mnew;
    float part = 0.f;
    #pragma unroll
    for (int j = 0; j < 4; j++)
      #pragma unroll
      for (int r = 0; r < 4; r++) {
        float pv = __expf(s[j][r] - mnew);
        s[j][r] = pv;
        part += pv;
      }
    psum = psum * alpha + part;

    // rescale O rows (O rows are quad*4+r; alpha lives at row lm -> gather)
    float ar_[4];
    #pragma unroll
    for (int r = 0; r < 4; r++)
      ar_[r] = __shfl(alpha, (lane & 48) | (quad * 4 + r), 64);
    #pragma unroll
    for (int j = 0; j < 4; j++)
      #pragma unroll
      for (int r = 0; r < 4; r++) oacc[j][r] *= ar_[r];

    // pack P pairs: u[2j]=keys(j*16+quad*4+{0,1}), u[2j+1]={2,3}
    uint32_t u[8];
    #pragma unroll
    for (int j = 0; j < 4; j++) {
      u[2 * j]     = cvtpk(s[j][0], s[j][1]);
      u[2 * j + 1] = cvtpk(s[j][2], s[j][3]);
    }

    __builtin_amdgcn_s_setprio(1);
    #pragma unroll
    for (int ks = 0; ks < 2; ++ks) {
      union { uint32_t w[4]; bf16x8 v; } cv;
      #pragma unroll
      for (int w = 0; w < 4; w++) {
        int lo = __builtin_amdgcn_ds_bpermute(w < 2 ? idx0 : idx1,
                                              (int)u[ks * 4 + (w & 1)]);
        int hi = __builtin_amdgcn_ds_bpermute(w < 2 ? idx0 : idx1,
                                              (int)u[ks * 4 + 2 + (w & 1)]);
        cv.w[w] = (quad < 2) ? (uint32_t)lo : (uint32_t)hi;
      }
      bf16x8 ap = cv.v;   // A-frag: P[q=lm][keys ks*32+quad*8 .. +7]
      #pragma unroll
      for (int j = 0; j < 4; j++) {
        int dg = 2 * j + (lm >> 3);
        int g  = (ks * 4 + quad) ^ (dg & 7);
        bf16x8 bv = asbf(ld8(&Vts[cur][(j * 16 + lm) * 64 + g * 8]));
        oacc[j] = __builtin_amdgcn_mfma_f32_16x16x32_bf16(ap, bv, oacc[j], 0, 0, 0);
      }
    }
    __builtin_amdgcn_s_setprio(0);
    __syncthreads();   // single per-iteration barrier (dbuf swap)
  }

  // epilogue: row sum lives at row lm; gather inv to O rows quad*4+r
  float s_ = psum;
  s_ += __shfl_xor(s_, 16, 64);
  s_ += __shfl_xor(s_, 32, 64);
  const float inv = 1.0f / s_;
  float ir_[4];
  #pragma unroll
  for (int r = 0; r < 4; r++)
    ir_[r] = __shfl(inv, (lane & 48) | (quad * 4 + r), 64);
  #pragma unroll
  for (int r = 0; r < 4; r++) {
    const int row = p * 64 + wave * 16 + quad * 4 + r;
    #pragma unroll
    for (int j = 0; j < 4; j++)
      Qh[(size_t)row * HD + j * 16 + lm] = f2b(oacc[j][r] * ir_[r]);
  }
}

// ---------------------------------------------------------------------------
// Output projection, 64x128 tiles, BK=64 dual-panel: grid (8, 64).
// d_out(f32) = ao @ Wo^T + bo ; ao in [N,16,L,64] bf16.
// ---------------------------------------------------------------------------
__global__ __launch_bounds__(256) void gemm_out(
    const u16* __restrict__ ao, const u16* __restrict__ Wo,
    const float* __restrict__ bo, float* __restrict__ out)
{
  __shared__ __align__(16) u16 As[64 * 64];    // 2 panels of 64x32
  __shared__ __align__(16) u16 Bs[128 * 64];   // 2 panels of 128x32
  const int m0 = blockIdx.y * 64, n0 = blockIdx.x * 128;
  const int tid  = threadIdx.x;
  const int lane = tid & 63;
  const int wave = tid >> 6;
  const int wm   = (wave >> 1) * 32;
  const int wn   = (wave & 1) * 64;
  const int ar   = tid >> 2;        // 0..63
  const int ac   = (tid & 3) * 8;
  const int lm   = lane & 15;
  const int lk   = (lane >> 4) * 8;

  f32x4 acc[2][4];
  #pragma unroll
  for (int i = 0; i < 2; i++)
    #pragma unroll
    for (int j = 0; j < 4; j++)
      #pragma unroll
      for (int e = 0; e < 4; e++) acc[i][j][e] = 0.f;

  for (int k0 = 0; k0 < EMB; k0 += 64) {
    size_t aoff[2];
    #pragma unroll
    for (int pnl = 0; pnl < 2; pnl++) {
      int kc = k0 + pnl * 32 + ac, h = kc >> 6, d = kc & 63;
      int r0 = m0 + ar;
      aoff[pnl] = (((size_t)((r0 >> 11) * NHEAD + h)) * SEQ + (r0 & (SEQ-1))) * HD + d;
    }
    __syncthreads();
    #pragma unroll
    for (int pnl = 0; pnl < 2; pnl++) {
      async_cp16(ao + aoff[pnl], As + pnl * 2048 + tid * 8);
      async_cp16(Wo + (size_t)(n0 + ar)      * EMB + k0 + pnl * 32 + ac, Bs + pnl * 4096 + tid * 8);
      async_cp16(Wo + (size_t)(n0 + ar + 64) * EMB + k0 + pnl * 32 + ac, Bs + pnl * 4096 + (tid + 256) * 8);
    }
    __syncthreads();

    #pragma unroll
    for (int pnl = 0; pnl < 2; pnl++) {
      bf16x8 af[2], bfr[4];
      #pragma unroll
      for (int i = 0; i < 2; i++)
        af[i] = asbf(ld8(As + pnl * 2048 + (wm + i * 16 + lm) * 32 + lk));
      #pragma unroll
      for (int j = 0; j < 4; j++)
        bfr[j] = asbf(ld8(Bs + pnl * 4096 + (wn + j * 16 + lm) * 32 + lk));
      #pragma unroll
      for (int i = 0; i < 2; i++)
        #pragma unroll
        for (int j = 0; j < 4; j++)
          acc[i][j] = __builtin_amdgcn_mfma_f32_16x16x32_bf16(af[i], bfr[j], acc[i][j], 0, 0, 0);
    }
  }

  const int quad = lane >> 4;
  #pragma unroll
  for (int j = 0; j < 4; j++) {
    int col = n0 + wn + j * 16 + lm;
    float bias = bo[col];
    #pragma unroll
    for (int i = 0; i < 2; i++)
      #pragma unroll
      for (int r = 0; r < 4; r++) {
        int row = m0 + wm + i * 16 + quad * 4 + r;
        out[(size_t)row * EMB + col] = acc[i][j][r] + bias;
      }
  }
}

extern "C" void kernel_launch(void* const* d_in, const int* in_sizes, int n_in,
                              void* d_out, int out_size, void* d_ws, size_t ws_size,
                              hipStream_t stream)
{
  const float* xf  = (const float*)d_in[0];
  const float* Wqf = (const float*)d_in[2];
  const float* Wkf = (const float*)d_in[3];
  const float* Wvf = (const float*)d_in[4];
  const float* gq  = (const float*)d_in[5];
  const float* bq  = (const float*)d_in[6];
  const float* gk  = (const float*)d_in[7];
  const float* bk  = (const float*)d_in[8];
  const float* Wof = (const float*)d_in[9];
  const float* bo  = (const float*)d_in[10];

  const size_t MB = 1u << 20;
  u16* xb  = (u16*)d_ws;                           // 8 MiB
  u16* wqb = xb  + (size_t)ROWS * EMB;             // 2 MiB each
  u16* wkb = wqb + (size_t)EMB * EMB;
  u16* wvb = wkb + (size_t)EMB * EMB;
  u16* wob = wvb + (size_t)EMB * EMB;
  u16* kvbase = wob + (size_t)EMB * EMB;           // ws + 16 MiB

  size_t avail = (ws_size > 16 * MB) ? ws_size - 16 * MB : 2 * MB;
  int hpp = NHEAD;
  while ((size_t)hpp * MB > avail && hpp > 2) hpp >>= 1;
  const size_t kv_elems = (size_t)hpp * NBATCH * SEQ * HD;
  u16* kbuf = kvbase;
  u16* vbuf = kbuf + kv_elems;

  // Q (bf16, + in-place attn output) lives in the x input buffer (dead
  // after cvt_all). gemm_out writes f32 straight to d_out.
  u16* qd = (u16*)d_in[0];
  float* out = (float*)d_out;

  cvt_all<<<dim3(8192), 256, 0, stream>>>(xf, Wqf, Wkf, Wvf, Wof,
                                          xb, wqb, wkb, wvb, wob);
  if (hpp == NHEAD) {
    gemm_qkv<<<dim3(8, 32, 3), 256, 0, stream>>>(xb, wqb, wkb, wvb,
                                                 gq, bq, gk, bk,
                                                 qd, kbuf, vbuf);
    attn<<<dim3(32, NHEAD, NBATCH), 256, 0, stream>>>(qd, kbuf, vbuf, 0, NHEAD);
  } else {
    gemm_q<<<dim3(8, 32), 256, 0, stream>>>(xb, wqb, gq, bq, qd);
    for (int g = 0; g < NHEAD / hpp; ++g) {
      gemm_kv<<<dim3(hpp / 2, 32, 2), 256, 0, stream>>>(xb, wkb, wvb, gk, bk,
                                                        kbuf, vbuf, g * hpp, hpp);
      attn<<<dim3(32, hpp, NBATCH), 256, 0, stream>>>(qd, kbuf, vbuf, g * hpp, hpp);
    }
  }
  gemm_out<<<dim3(8, 64), 256, 0, stream>>>(qd, wob, bo, out);
}